// Round 12
// baseline (736.582 us; speedup 1.0000x reference)
//
#include <hip/hip_runtime.h>
#include <hip/hip_bf16.h>
#include <cstdint>

#define DIM   2048
#define MROWS 16384  // B*S = 8*2048
#define NH    64     // K halves of 32

typedef __bf16 bf16x8 __attribute__((ext_vector_type(8)));
typedef float  f32x4  __attribute__((ext_vector_type(4)));
typedef unsigned short u16;
typedef unsigned int   u32;

#define BARRIER() asm volatile("s_barrier" ::: "memory")
#define WAITVM(N) asm volatile("s_waitcnt vmcnt(" #N ")" ::: "memory")

// ---- ws layout (bytes), total 160 MiB ----
// [0,         25165824) : ternary bf16 Wf,Wc,Wg   (3 x 2048x2048 x 2B)
// [25165824,  33554432) : ternary bf16 Wo
// [33554432, 100663296) : x cast to bf16          (16384x2048 x 2B)
// [100663296,167772160) : gh = g*h bf16           (16384x2048 x 2B)

__device__ __forceinline__ u16 ternary_bits(float w) {
    u32 u = __float_as_uint(w);
    u16 s = (u16)((u >> 16) & 0x8000u);
    return (__builtin_fabsf(w) < 0.33f) ? (u16)0 : (u16)(0x3F80u | s);
}

__device__ __forceinline__ u16 f2bf_rne(float f) {
    u32 u = __float_as_uint(f);
    u32 r = (u + 0x7FFFu + ((u >> 16) & 1u)) >> 16;
    return (u16)r;
}

__device__ __forceinline__ void gload16(const void* g, void* l) {
    __builtin_amdgcn_global_load_lds(
        (const __attribute__((address_space(1))) void*)g,
        (__attribute__((address_space(3))) void*)l,
        16, 0, 0);
}

// ---------------- prep kernels ----------------

__global__ void prep_weights(const float* __restrict__ wf, const float* __restrict__ wc,
                             const float* __restrict__ wg, const float* __restrict__ wo,
                             u16* __restrict__ out) {
    const float* srcs[4] = {wf, wc, wg, wo};
    const float* src = srcs[blockIdx.y];
    u16* dst = out + (size_t)blockIdx.y * (DIM * DIM);
    int e = (blockIdx.x * 256 + threadIdx.x) * 8;
    float4 v0 = *(const float4*)(src + e);
    float4 v1 = *(const float4*)(src + e + 4);
    ushort4 o0, o1;
    o0.x = ternary_bits(v0.x); o0.y = ternary_bits(v0.y);
    o0.z = ternary_bits(v0.z); o0.w = ternary_bits(v0.w);
    o1.x = ternary_bits(v1.x); o1.y = ternary_bits(v1.y);
    o1.z = ternary_bits(v1.z); o1.w = ternary_bits(v1.w);
    *(ushort4*)(dst + e)     = o0;
    *(ushort4*)(dst + e + 4) = o1;
}

__global__ void cast_x(const float* __restrict__ x, u16* __restrict__ xb) {
    size_t e = ((size_t)blockIdx.x * 256 + threadIdx.x) * 8;
    float4 v0 = *(const float4*)(x + e);
    float4 v1 = *(const float4*)(x + e + 4);
    ushort4 o0, o1;
    o0.x = f2bf_rne(v0.x); o0.y = f2bf_rne(v0.y);
    o0.z = f2bf_rne(v0.z); o0.w = f2bf_rne(v0.w);
    o1.x = f2bf_rne(v1.x); o1.y = f2bf_rne(v1.y);
    o1.z = f2bf_rne(v1.z); o1.w = f2bf_rne(v1.w);
    *(ushort4*)(xb + e)     = o0;
    *(ushort4*)(xb + e + 4) = o1;
}

// ---------------- fused GEMM1: f/c/g preacts + activations + h + gh ----------------
// Identical compute body to R11 (256 thr, 4 waves 2x2, wave tile 64x64/gate,
// dbuf 2x32KB, 2 blocks/CU). ONLY change: grid traversal n-fastest/m-slowest —
// XCD chunk = 16 m-tiles x all 16 n-tiles, so 16 consecutive blocks share one
// 512KB x-tile (L2-resident) and chip-wide x footprint ~8MB (L3-stable);
// fixes the 3.2x HBM over-fetch of x (FETCH 690MB vs ideal 216MB).

__global__ __launch_bounds__(256, 2) void gemm1(
    const u16* __restrict__ xb,      // [16384][2048] bf16
    const u16* __restrict__ wt,      // [3][2048][2048] bf16 ternary (f,c,g)
    const float* __restrict__ bfv_, const float* __restrict__ bcv_, const float* __restrict__ bgv_,
    const float* __restrict__ hprev, // [16384][2048] f32
    float* __restrict__ hout,        // f32, second half of d_out
    u16* __restrict__ gh)            // bf16 ws
{
    __shared__ __align__(16) u16 lds[2][16384];   // 2 x 32KB slots

    const int tid  = threadIdx.x;
    const int lane = tid & 63;
    const int wave = tid >> 6;    // 0..3
    const int wr   = wave >> 1;   // 0..1 -> 64-row half
    const int wcq  = wave & 1;    // 0..1 -> 64-col half

    // grid: 2048 blocks = 8 XCD chunks x 256; within chunk: n fastest (16),
    // m slow (16) -> consecutive blocks share the same x-tile.
    const int bid   = blockIdx.x;
    const int chunk = bid >> 8;          // 0..7 (XCD)
    const int inner = bid & 255;
    const int mtile = chunk * 16 + (inner >> 4);   // 0..127
    const int ntile = inner & 15;                  // 0..15
    const int brow  = mtile * 128;
    const int bcol  = ntile * 128;

    // staging: pass = 256 thr x 16B = 4KB = 64 rows x 64B; thread t -> row t>>2,
    // 16B chunk (t&3); source chunk XOR ((row>>1)&3) = ((t>>3)&3)  [involution]
    const int row64 = tid >> 2;                       // 0..63
    const int gc4   = (tid & 3) ^ ((tid >> 3) & 3);   // swizzled source chunk
    const int ldst  = tid * 8;                        // u16 offset within 4KB pass

    const int fr  = lane & 15;
    const int hi  = lane >> 4;                        // 0..3
    const int csw = (hi ^ ((fr >> 1) & 3)) * 8;       // swizzled read chunk (u16)

    f32x4 acc[3][4][4] = {};   // [gate][mi][ni] — fully static indexing

    const u16* aSrc = xb + (size_t)(brow + row64) * DIM;
    const u16* bSrc = wt + (size_t)(bcol + row64) * DIM;
    const size_t WST = (size_t)DIM * DIM;

    auto issueHalf = [&](int slot, int k0) {
        gload16(aSrc + k0 + gc4 * 8,                        (u16*)&lds[slot][ldst]);
        gload16(aSrc + (size_t)64 * DIM + k0 + gc4 * 8,     (u16*)&lds[slot][2048 + ldst]);
        #pragma unroll
        for (int g = 0; g < 3; ++g) {
            gload16(bSrc + (size_t)g * WST + k0 + gc4 * 8,
                    (u16*)&lds[slot][(2 + 2 * g) * 2048 + ldst]);
            gload16(bSrc + (size_t)g * WST + (size_t)64 * DIM + k0 + gc4 * 8,
                    (u16*)&lds[slot][(3 + 2 * g) * 2048 + ldst]);
        }
    };

    auto rdA = [&](const u16* sl, bf16x8 (&a)[4]) {
        #pragma unroll
        for (int mi = 0; mi < 4; ++mi)
            a[mi] = *(const bf16x8*)(sl + (wr * 64 + mi * 16 + fr) * 32 + csw);
    };

    // prologue: stage half 0, drain, barrier
    issueHalf(0, 0);
    WAITVM(0);
    BARRIER();

    #pragma unroll 1
    for (int j = 0; j < NH; ++j) {
        const u16* sl = &lds[j & 1][0];
        bf16x8 a[4];
        rdA(sl, a);
        if (j + 1 < NH) issueHalf((j + 1) & 1, (j + 1) * 32);
        #pragma unroll
        for (int ni = 0; ni < 4; ++ni) {
            bf16x8 b[3];
            #pragma unroll
            for (int g = 0; g < 3; ++g)
                b[g] = *(const bf16x8*)(sl + 4096 + g * 4096 + (wcq * 64 + ni * 16 + fr) * 32 + csw);
            __builtin_amdgcn_s_setprio(1);
            #pragma unroll
            for (int g = 0; g < 3; ++g)
                #pragma unroll
                for (int mi = 0; mi < 4; ++mi)
                    acc[g][mi][ni] = __builtin_amdgcn_mfma_f32_16x16x32_bf16(a[mi], b[g], acc[g][mi][ni], 0, 0, 0);
            __builtin_amdgcn_s_setprio(0);
        }
        if (j + 1 < NH) {
            WAITVM(0);    // all waves drain own stage loads, then
            BARRIER();    // barrier => slot j+1 fully written, slot j reads done
        }
    }

    // fused epilogue: f=sigmoid, c=silu, g=sigmoid, h=f*hp+(1-f)*c, gh=g*h
    #pragma unroll
    for (int ni = 0; ni < 4; ++ni) {
        const int col = bcol + wcq * 64 + ni * 16 + fr;
        const float bfv = bfv_[col], bcv = bcv_[col], bgv = bgv_[col];
        #pragma unroll
        for (int mi = 0; mi < 4; ++mi) {
            #pragma unroll
            for (int jj = 0; jj < 4; ++jj) {
                const int row = brow + wr * 64 + mi * 16 + hi * 4 + jj;
                const size_t idx = (size_t)row * DIM + col;
                float pf = acc[0][mi][ni][jj] + bfv;
                float pc = acc[1][mi][ni][jj] + bcv;
                float pg = acc[2][mi][ni][jj] + bgv;
                float f  = 1.f / (1.f + __expf(-pf));
                float cc = pc / (1.f + __expf(-pc));
                float g  = 1.f / (1.f + __expf(-pg));
                float hh = f * hprev[idx] + (1.f - f) * cc;
                hout[idx] = hh;
                gh[idx] = f2bf_rne(g * hh);
            }
        }
    }
}

// ---------------- GEMM2: o = gh @ Wo^T + bo ----------------
// R8 body; grid remapped n-fastest/m-slowest (8 consecutive blocks share one
// 1MB gh-tile -> L2-resident; Wo 8MB L3-resident).

__global__ __launch_bounds__(512) void gemm2(
    const u16* __restrict__ gh,    // [16384][2048] bf16
    const u16* __restrict__ wot,   // [2048][2048] bf16 ternary
    const float* __restrict__ bov_,
    float* __restrict__ oout)      // f32, first half of d_out
{
    __shared__ __align__(16) u16 lds[3 * 16384];   // 96 KB: slot = A[8192] + B[8192]

    const int tid  = threadIdx.x;
    const int lane = tid & 63;
    const int wave = tid >> 6;
    const int wr   = wave >> 2;   // 0..1 -> 128-row half
    const int wcq  = wave & 3;    // 0..3 -> 64-col quarter

    // grid: 512 blocks = 8 chunks x 64; within chunk n fastest (8), m slow (8)
    const int bid   = blockIdx.x;
    const int chunk = bid >> 6;          // 0..7
    const int inner = bid & 63;
    const int mtile = chunk * 8 + (inner >> 3);   // 0..63
    const int ntile = inner & 7;                  // 0..7
    const int brow  = mtile * 256;
    const int bcol  = ntile * 256;

    const int srow = tid >> 2;
    const int gc4  = (tid & 3) ^ ((tid >> 3) & 3);
    const int ldst = tid * 8;

    const int fr  = lane & 15;
    const int hi  = lane >> 4;
    const int csw = (hi ^ ((fr >> 1) & 3)) * 8;

    f32x4 accL[8][2] = {};   // ni 0..1
    f32x4 accH[8][2] = {};   // ni 2..3

    const u16* aSrc0 = gh  + (size_t)(brow + srow) * DIM;
    const u16* aSrc1 = gh  + (size_t)(brow + 128 + srow) * DIM;
    const u16* bSrc0 = wot + (size_t)(bcol + srow) * DIM;
    const u16* bSrc1 = wot + (size_t)(bcol + 128 + srow) * DIM;

    auto issueA = [&](int so, int k0) {
        gload16(aSrc0 + k0 + gc4 * 8, (u16*)&lds[so + ldst]);
        gload16(aSrc1 + k0 + gc4 * 8, (u16*)&lds[so + 4096 + ldst]);
    };
    auto issueB = [&](int so, int k0) {
        gload16(bSrc0 + k0 + gc4 * 8, (u16*)&lds[so + 8192 + ldst]);
        gload16(bSrc1 + k0 + gc4 * 8, (u16*)&lds[so + 12288 + ldst]);
    };

    auto rdA = [&](int so, bf16x8 (&a)[8]) {
        #pragma unroll
        for (int mi = 0; mi < 8; ++mi)
            a[mi] = *(const bf16x8*)(&lds[so + (wr * 128 + mi * 16 + fr) * 32 + csw]);
    };
    auto rdBL = [&](int so, bf16x8 (&b)[2]) {
        #pragma unroll
        for (int jn = 0; jn < 2; ++jn)
            b[jn] = *(const bf16x8*)(&lds[so + 8192 + (wcq * 64 + jn * 16 + fr) * 32 + csw]);
    };
    auto rdBH = [&](int so, bf16x8 (&b)[2]) {
        #pragma unroll
        for (int jn = 0; jn < 2; ++jn)
            b[jn] = *(const bf16x8*)(&lds[so + 8192 + (wcq * 64 + (2 + jn) * 16 + fr) * 32 + csw]);
    };
    auto mfma2 = [&](bf16x8 (&a)[8], bf16x8 (&b)[2], f32x4 (&c)[8][2]) {
        __builtin_amdgcn_s_setprio(1);
        #pragma unroll
        for (int jn = 0; jn < 2; ++jn)
            #pragma unroll
            for (int mi = 0; mi < 8; ++mi)
                c[mi][jn] = __builtin_amdgcn_mfma_f32_16x16x32_bf16(a[mi], b[jn], c[mi][jn], 0, 0, 0);
        __builtin_amdgcn_s_setprio(0);
    };

    int so0 = 0, so1 = 16384, so2 = 32768;

    bf16x8 aP[8], bLP[2], aQ[8], bLQ[2], bH[2];

    // prologue: halves 0,1; retire h0; read a(0), bL(0)
    issueA(so0, 0); issueB(so0, 0);
    issueA(so1, 32); issueB(so1, 32);
    WAITVM(4);
    BARRIER();
    rdA(so0, aP); rdBL(so0, bLP);

    auto step = [&](int h, bf16x8 (&aC)[8], bf16x8 (&bLC)[2],
                    bf16x8 (&aN)[8], bf16x8 (&bLN)[2]) {
        const int kn = (h + 2) * 32;
        // P0
        rdBH(so0, bH);
        issueA(so2, kn);                 // outstanding: A(h+1),B(h+1),A(h+2) = 6
        mfma2(aC, bLC, accL);
        // P1
        WAITVM(2);                       // retire half h+1
        BARRIER();
        rdA(so1, aN); rdBL(so1, bLN);
        issueB(so2, kn);                 // outstanding: A(h+2),B(h+2) = 4
        mfma2(aC, bH, accH);
        BARRIER();
        int t = so0; so0 = so1; so1 = so2; so2 = t;
    };

    #pragma unroll 1
    for (int h = 0; h < NH - 2; h += 2) {   // h = 0..61 (31 pairs -> ends at P)
        step(h,     aP, bLP, aQ, bLQ);
        step(h + 1, aQ, bLQ, aP, bLP);
    }
    { // h = NH-2 (62): no issue; outstanding {A63,B63}=4 -> WAITVM(0)
        rdBH(so0, bH);
        mfma2(aP, bLP, accL);
        WAITVM(0);
        BARRIER();
        rdA(so1, aQ); rdBL(so1, bLQ);
        mfma2(aP, bH, accH);
        BARRIER();
        int t = so0; so0 = so1; so1 = so2; so2 = t;
    }
    { // h = NH-1 (63): all resident
        rdBH(so0, bH);
        mfma2(aQ, bLQ, accL);
        mfma2(aQ, bH, accH);
    }

    auto epi2 = [&](int nbase, f32x4 (&c)[8][2]) {
        #pragma unroll
        for (int jn = 0; jn < 2; ++jn) {
            const int col = bcol + wcq * 64 + (nbase + jn) * 16 + fr;
            const float bov = bov_[col];
            #pragma unroll
            for (int mi = 0; mi < 8; ++mi)
                #pragma unroll
                for (int j = 0; j < 4; ++j)
                    oout[(size_t)(brow + wr * 128 + mi * 16 + hi * 4 + j) * DIM + col] = c[mi][jn][j] + bov;
        }
    };
    epi2(0, accL);
    epi2(2, accH);
}

extern "C" void kernel_launch(void* const* d_in, const int* in_sizes, int n_in,
                              void* d_out, int out_size, void* d_ws, size_t ws_size,
                              hipStream_t stream) {
    const float* x  = (const float*)d_in[0];
    const float* hp = (const float*)d_in[1];
    const float* wf = (const float*)d_in[2];
    const float* bf = (const float*)d_in[3];
    const float* wc = (const float*)d_in[4];
    const float* bc = (const float*)d_in[5];
    const float* wg = (const float*)d_in[6];
    const float* bg = (const float*)d_in[7];
    const float* wo = (const float*)d_in[8];
    const float* bo = (const float*)d_in[9];

    float* o_out = (float*)d_out;
    float* h_out = o_out + (size_t)MROWS * DIM;

    u16* w_t  = (u16*)d_ws;                              // wf,wc,wg then wo
    u16* x_bf = (u16*)((char*)d_ws + 33554432);
    u16* gh   = (u16*)((char*)d_ws + 100663296);

    prep_weights<<<dim3(2048, 4), 256, 0, stream>>>(wf, wc, wg, wo, w_t);
    cast_x<<<dim3(16384), 256, 0, stream>>>(x, x_bf);
    gemm1<<<dim3(2048), 256, 0, stream>>>(x_bf, w_t, bf, bc, bg, hp, h_out, gh);
    gemm2<<<dim3(512), 512, 0, stream>>>(gh, w_t + 3 * (size_t)DIM * DIM, bo, o_out);
}

// Round 13
// 699.752 us; speedup vs baseline: 1.0526x; 1.0526x over previous
//
#include <hip/hip_runtime.h>
#include <hip/hip_bf16.h>
#include <cstdint>

#define DIM   2048
#define MROWS 16384  // B*S = 8*2048
#define NH    64     // K halves of 32

typedef __bf16 bf16x8 __attribute__((ext_vector_type(8)));
typedef float  f32x4  __attribute__((ext_vector_type(4)));
typedef unsigned short u16;
typedef unsigned int   u32;

#define BARRIER() asm volatile("s_barrier" ::: "memory")
#define WAITVM(N) asm volatile("s_waitcnt vmcnt(" #N ")" ::: "memory")

// ---- ws layout (bytes), total 160 MiB ----
// [0,         25165824) : ternary bf16 Wf,Wc,Wg   (3 x 2048x2048 x 2B)
// [25165824,  33554432) : ternary bf16 Wo
// [33554432, 100663296) : x cast to bf16          (16384x2048 x 2B)
// [100663296,167772160) : gh = g*h bf16           (16384x2048 x 2B)

__device__ __forceinline__ u16 ternary_bits(float w) {
    u32 u = __float_as_uint(w);
    u16 s = (u16)((u >> 16) & 0x8000u);
    return (__builtin_fabsf(w) < 0.33f) ? (u16)0 : (u16)(0x3F80u | s);
}

__device__ __forceinline__ u16 f2bf_rne(float f) {
    u32 u = __float_as_uint(f);
    u32 r = (u + 0x7FFFu + ((u >> 16) & 1u)) >> 16;
    return (u16)r;
}

__device__ __forceinline__ void gload16(const void* g, void* l) {
    __builtin_amdgcn_global_load_lds(
        (const __attribute__((address_space(1))) void*)g,
        (__attribute__((address_space(3))) void*)l,
        16, 0, 0);
}

// ---------------- prep kernels ----------------

__global__ void prep_weights(const float* __restrict__ wf, const float* __restrict__ wc,
                             const float* __restrict__ wg, const float* __restrict__ wo,
                             u16* __restrict__ out) {
    const float* srcs[4] = {wf, wc, wg, wo};
    const float* src = srcs[blockIdx.y];
    u16* dst = out + (size_t)blockIdx.y * (DIM * DIM);
    int e = (blockIdx.x * 256 + threadIdx.x) * 8;
    float4 v0 = *(const float4*)(src + e);
    float4 v1 = *(const float4*)(src + e + 4);
    ushort4 o0, o1;
    o0.x = ternary_bits(v0.x); o0.y = ternary_bits(v0.y);
    o0.z = ternary_bits(v0.z); o0.w = ternary_bits(v0.w);
    o1.x = ternary_bits(v1.x); o1.y = ternary_bits(v1.y);
    o1.z = ternary_bits(v1.z); o1.w = ternary_bits(v1.w);
    *(ushort4*)(dst + e)     = o0;
    *(ushort4*)(dst + e + 4) = o1;
}

__global__ void cast_x(const float* __restrict__ x, u16* __restrict__ xb) {
    size_t e = ((size_t)blockIdx.x * 256 + threadIdx.x) * 8;
    float4 v0 = *(const float4*)(x + e);
    float4 v1 = *(const float4*)(x + e + 4);
    ushort4 o0, o1;
    o0.x = f2bf_rne(v0.x); o0.y = f2bf_rne(v0.y);
    o0.z = f2bf_rne(v0.z); o0.w = f2bf_rne(v0.w);
    o1.x = f2bf_rne(v1.x); o1.y = f2bf_rne(v1.y);
    o1.z = f2bf_rne(v1.z); o1.w = f2bf_rne(v1.w);
    *(ushort4*)(xb + e)     = o0;
    *(ushort4*)(xb + e + 4) = o1;
}

// ---------------- fused GEMM1: f/c/g preacts + activations + h + gh ----------------
// R11 geometry (256 thr, 4 waves 2x2, wave 64x64/gate, dbuf 2x32KB, 2 blocks/CU,
// m-fastest XCD grid). NEW: 4-phase fine interleave per k32 (m201/T3 pattern):
//   phase p (=ni): { 3 ds_read B (+4 A reads & 10 gload issues at p0)
//                    -> BARRIER -> 12-MFMA cluster (setprio) -> BARRIER }
// One WAITVM(0) per k32 at p3 (stage had 3 phases to land). With 2 blocks/CU the
// anti-phase waves keep both LDS and MFMA pipes continuously fed.

__global__ __launch_bounds__(256, 2) void gemm1(
    const u16* __restrict__ xb,      // [16384][2048] bf16
    const u16* __restrict__ wt,      // [3][2048][2048] bf16 ternary (f,c,g)
    const float* __restrict__ bfv_, const float* __restrict__ bcv_, const float* __restrict__ bgv_,
    const float* __restrict__ hprev, // [16384][2048] f32
    float* __restrict__ hout,        // f32, second half of d_out
    u16* __restrict__ gh)            // bf16 ws
{
    __shared__ __align__(16) u16 lds[2][16384];   // 2 x 32KB slots

    const int tid  = threadIdx.x;
    const int lane = tid & 63;
    const int wave = tid >> 6;    // 0..3
    const int wr   = wave >> 1;   // 0..1 -> 64-row half
    const int wcq  = wave & 1;    // 0..1 -> 64-col half

    const int bid  = blockIdx.x;                     // 2048 = 128 m x 16 n
    const int swz  = (bid & 7) * 256 + (bid >> 3);   // XCD-contiguous, m-fastest
    const int brow = (swz & 127) * 128;
    const int bcol = (swz >> 7) * 128;

    const int row64 = tid >> 2;                       // 0..63
    const int gc4   = (tid & 3) ^ ((tid >> 3) & 3);   // swizzled source chunk
    const int ldst  = tid * 8;                        // u16 offset within 4KB pass

    const int fr  = lane & 15;
    const int hi  = lane >> 4;                        // 0..3
    const int csw = (hi ^ ((fr >> 1) & 3)) * 8;       // swizzled read chunk (u16)

    f32x4 acc[3][4][4] = {};   // [gate][mi][ni] — all indices compile-time

    const u16* aSrc = xb + (size_t)(brow + row64) * DIM;
    const u16* bSrc = wt + (size_t)(bcol + row64) * DIM;
    const size_t WST = (size_t)DIM * DIM;

    auto issueHalf = [&](int slot, int k0) {
        gload16(aSrc + k0 + gc4 * 8,                        (u16*)&lds[slot][ldst]);
        gload16(aSrc + (size_t)64 * DIM + k0 + gc4 * 8,     (u16*)&lds[slot][2048 + ldst]);
        #pragma unroll
        for (int g = 0; g < 3; ++g) {
            gload16(bSrc + (size_t)g * WST + k0 + gc4 * 8,
                    (u16*)&lds[slot][(2 + 2 * g) * 2048 + ldst]);
            gload16(bSrc + (size_t)g * WST + (size_t)64 * DIM + k0 + gc4 * 8,
                    (u16*)&lds[slot][(3 + 2 * g) * 2048 + ldst]);
        }
    };

    // prologue: stage half 0, drain, barrier
    issueHalf(0, 0);
    WAITVM(0);
    BARRIER();

    bf16x8 a[4], b[3];

#define RD_B(NI)                                                                      \
    _Pragma("unroll")                                                                 \
    for (int g = 0; g < 3; ++g)                                                       \
        b[g] = *(const bf16x8*)(sl + 4096 + g * 4096 + (wcq * 64 + (NI) * 16 + fr) * 32 + csw);

#define MFMA_NI(NI)                                                                   \
    __builtin_amdgcn_s_setprio(1);                                                    \
    _Pragma("unroll")                                                                 \
    for (int g = 0; g < 3; ++g)                                                       \
        _Pragma("unroll")                                                             \
        for (int mi = 0; mi < 4; ++mi)                                                \
            acc[g][mi][NI] = __builtin_amdgcn_mfma_f32_16x16x32_bf16(a[mi], b[g], acc[g][mi][NI], 0, 0, 0); \
    __builtin_amdgcn_s_setprio(0);

    #pragma unroll 1
    for (int j = 0; j < NH; ++j) {
        const u16* sl = &lds[j & 1][0];
        // p0: A reads + B(ni0) + stage issue
        #pragma unroll
        for (int mi = 0; mi < 4; ++mi)
            a[mi] = *(const bf16x8*)(sl + (wr * 64 + mi * 16 + fr) * 32 + csw);
        RD_B(0);
        if (j + 1 < NH) issueHalf((j + 1) & 1, (j + 1) * 32);
        BARRIER();
        MFMA_NI(0);
        BARRIER();
        // p1
        RD_B(1);
        BARRIER();
        MFMA_NI(1);
        BARRIER();
        // p2
        RD_B(2);
        BARRIER();
        MFMA_NI(2);
        BARRIER();
        // p3: drain stage (had 3 phases of slack), then last cluster
        RD_B(3);
        if (j + 1 < NH) WAITVM(0);
        BARRIER();
        MFMA_NI(3);
        BARRIER();
    }
#undef RD_B
#undef MFMA_NI

    // fused epilogue: f=sigmoid, c=silu, g=sigmoid, h=f*hp+(1-f)*c, gh=g*h
    #pragma unroll
    for (int ni = 0; ni < 4; ++ni) {
        const int col = bcol + wcq * 64 + ni * 16 + fr;
        const float bfv = bfv_[col], bcv = bcv_[col], bgv = bgv_[col];
        #pragma unroll
        for (int mi = 0; mi < 4; ++mi) {
            #pragma unroll
            for (int jj = 0; jj < 4; ++jj) {
                const int row = brow + wr * 64 + mi * 16 + hi * 4 + jj;
                const size_t idx = (size_t)row * DIM + col;
                float pf = acc[0][mi][ni][jj] + bfv;
                float pc = acc[1][mi][ni][jj] + bcv;
                float pg = acc[2][mi][ni][jj] + bgv;
                float f  = 1.f / (1.f + __expf(-pf));
                float cc = pc / (1.f + __expf(-pc));
                float g  = 1.f / (1.f + __expf(-pg));
                float hh = f * hprev[idx] + (1.f - f) * cc;
                hout[idx] = hh;
                gh[idx] = f2bf_rne(g * hh);
            }
        }
    }
}

// ---------------- GEMM2: o = gh @ Wo^T + bo ----------------
// (R11 version verbatim — grid reverted to m-fastest; isolating gemm1's change)

__global__ __launch_bounds__(512) void gemm2(
    const u16* __restrict__ gh,    // [16384][2048] bf16
    const u16* __restrict__ wot,   // [2048][2048] bf16 ternary
    const float* __restrict__ bov_,
    float* __restrict__ oout)      // f32, first half of d_out
{
    __shared__ __align__(16) u16 lds[3 * 16384];   // 96 KB: slot = A[8192] + B[8192]

    const int tid  = threadIdx.x;
    const int lane = tid & 63;
    const int wave = tid >> 6;
    const int wr   = wave >> 2;   // 0..1 -> 128-row half
    const int wcq  = wave & 3;    // 0..3 -> 64-col quarter

    const int bid  = blockIdx.x;                   // 512 = 64 m x 8 n
    const int swz  = (bid & 7) * 64 + (bid >> 3);  // one n-column per XCD
    const int brow = (swz & 63) * 256;
    const int bcol = (swz >> 6) * 256;

    const int srow = tid >> 2;
    const int gc4  = (tid & 3) ^ ((tid >> 3) & 3);
    const int ldst = tid * 8;

    const int fr  = lane & 15;
    const int hi  = lane >> 4;
    const int csw = (hi ^ ((fr >> 1) & 3)) * 8;

    f32x4 accL[8][2] = {};   // ni 0..1
    f32x4 accH[8][2] = {};   // ni 2..3

    const u16* aSrc0 = gh  + (size_t)(brow + srow) * DIM;
    const u16* aSrc1 = gh  + (size_t)(brow + 128 + srow) * DIM;
    const u16* bSrc0 = wot + (size_t)(bcol + srow) * DIM;
    const u16* bSrc1 = wot + (size_t)(bcol + 128 + srow) * DIM;

    auto issueA = [&](int so, int k0) {
        gload16(aSrc0 + k0 + gc4 * 8, (u16*)&lds[so + ldst]);
        gload16(aSrc1 + k0 + gc4 * 8, (u16*)&lds[so + 4096 + ldst]);
    };
    auto issueB = [&](int so, int k0) {
        gload16(bSrc0 + k0 + gc4 * 8, (u16*)&lds[so + 8192 + ldst]);
        gload16(bSrc1 + k0 + gc4 * 8, (u16*)&lds[so + 12288 + ldst]);
    };

    auto rdA = [&](int so, bf16x8 (&a)[8]) {
        #pragma unroll
        for (int mi = 0; mi < 8; ++mi)
            a[mi] = *(const bf16x8*)(&lds[so + (wr * 128 + mi * 16 + fr) * 32 + csw]);
    };
    auto rdBL = [&](int so, bf16x8 (&b)[2]) {
        #pragma unroll
        for (int jn = 0; jn < 2; ++jn)
            b[jn] = *(const bf16x8*)(&lds[so + 8192 + (wcq * 64 + jn * 16 + fr) * 32 + csw]);
    };
    auto rdBH = [&](int so, bf16x8 (&b)[2]) {
        #pragma unroll
        for (int jn = 0; jn < 2; ++jn)
            b[jn] = *(const bf16x8*)(&lds[so + 8192 + (wcq * 64 + (2 + jn) * 16 + fr) * 32 + csw]);
    };
    auto mfma2 = [&](bf16x8 (&a)[8], bf16x8 (&b)[2], f32x4 (&c)[8][2]) {
        __builtin_amdgcn_s_setprio(1);
        #pragma unroll
        for (int jn = 0; jn < 2; ++jn)
            #pragma unroll
            for (int mi = 0; mi < 8; ++mi)
                c[mi][jn] = __builtin_amdgcn_mfma_f32_16x16x32_bf16(a[mi], b[jn], c[mi][jn], 0, 0, 0);
        __builtin_amdgcn_s_setprio(0);
    };

    int so0 = 0, so1 = 16384, so2 = 32768;

    bf16x8 aP[8], bLP[2], aQ[8], bLQ[2], bH[2];

    // prologue: halves 0,1; retire h0; read a(0), bL(0)
    issueA(so0, 0); issueB(so0, 0);
    issueA(so1, 32); issueB(so1, 32);
    WAITVM(4);
    BARRIER();
    rdA(so0, aP); rdBL(so0, bLP);

    auto step = [&](int h, bf16x8 (&aC)[8], bf16x8 (&bLC)[2],
                    bf16x8 (&aN)[8], bf16x8 (&bLN)[2]) {
        const int kn = (h + 2) * 32;
        // P0
        rdBH(so0, bH);
        issueA(so2, kn);                 // outstanding: A(h+1),B(h+1),A(h+2) = 6
        mfma2(aC, bLC, accL);
        // P1
        WAITVM(2);                       // retire half h+1
        BARRIER();
        rdA(so1, aN); rdBL(so1, bLN);
        issueB(so2, kn);                 // outstanding: A(h+2),B(h+2) = 4
        mfma2(aC, bH, accH);
        BARRIER();
        int t = so0; so0 = so1; so1 = so2; so2 = t;
    };

    #pragma unroll 1
    for (int h = 0; h < NH - 2; h += 2) {   // h = 0..61 (31 pairs -> ends at P)
        step(h,     aP, bLP, aQ, bLQ);
        step(h + 1, aQ, bLQ, aP, bLP);
    }
    { // h = NH-2 (62): no issue; outstanding {A63,B63}=4 -> WAITVM(0)
        rdBH(so0, bH);
        mfma2(aP, bLP, accL);
        WAITVM(0);
        BARRIER();
        rdA(so1, aQ); rdBL(so1, bLQ);
        mfma2(aP, bH, accH);
        BARRIER();
        int t = so0; so0 = so1; so1 = so2; so2 = t;
    }
    { // h = NH-1 (63): all resident
        rdBH(so0, bH);
        mfma2(aQ, bLQ, accL);
        mfma2(aQ, bH, accH);
    }

    auto epi2 = [&](int nbase, f32x4 (&c)[8][2]) {
        #pragma unroll
        for (int jn = 0; jn < 2; ++jn) {
            const int col = bcol + wcq * 64 + (nbase + jn) * 16 + fr;
            const float bov = bov_[col];
            #pragma unroll
            for (int mi = 0; mi < 8; ++mi)
                #pragma unroll
                for (int j = 0; j < 4; ++j)
                    oout[(size_t)(brow + wr * 128 + mi * 16 + hi * 4 + j) * DIM + col] = c[mi][jn][j] + bov;
        }
    };
    epi2(0, accL);
    epi2(2, accH);
}

extern "C" void kernel_launch(void* const* d_in, const int* in_sizes, int n_in,
                              void* d_out, int out_size, void* d_ws, size_t ws_size,
                              hipStream_t stream) {
    const float* x  = (const float*)d_in[0];
    const float* hp = (const float*)d_in[1];
    const float* wf = (const float*)d_in[2];
    const float* bf = (const float*)d_in[3];
    const float* wc = (const float*)d_in[4];
    const float* bc = (const float*)d_in[5];
    const float* wg = (const float*)d_in[6];
    const float* bg = (const float*)d_in[7];
    const float* wo = (const float*)d_in[8];
    const float* bo = (const float*)d_in[9];

    float* o_out = (float*)d_out;
    float* h_out = o_out + (size_t)MROWS * DIM;

    u16* w_t  = (u16*)d_ws;                              // wf,wc,wg then wo
    u16* x_bf = (u16*)((char*)d_ws + 33554432);
    u16* gh   = (u16*)((char*)d_ws + 100663296);

    prep_weights<<<dim3(2048, 4), 256, 0, stream>>>(wf, wc, wg, wo, w_t);
    cast_x<<<dim3(16384), 256, 0, stream>>>(x, x_bf);
    gemm1<<<dim3(2048), 256, 0, stream>>>(x_bf, w_t, bf, bc, bg, hp, h_out, gh);
    gemm2<<<dim3(512), 512, 0, stream>>>(gh, w_t + 3 * (size_t)DIM * DIM, bo, o_out);
}